// Round 11
// baseline (357.035 us; speedup 1.0000x reference)
//
#include <hip/hip_runtime.h>

typedef __bf16 bf16;
typedef __bf16 bf16x8 __attribute__((ext_vector_type(8)));
typedef float  f32x4  __attribute__((ext_vector_type(4)));

#define L_SEQ 1024
#define DM    1024
#define DI    2048
#define DTR   64
#define DSTATE 16
#define XD    96   // DT_RANK + 2*D_STATE
#define NC    64   // scan chunks
#define CS    16   // steps per chunk

__device__ __forceinline__ float bf2f(bf16 v){ return (float)v; }
__device__ __forceinline__ bf16  f2bf(float v){ return (bf16)v; }

// async global->LDS, 16B per lane; LDS dest = wave-uniform base + lane*16
__device__ __forceinline__ void gl_lds16(const bf16* g, bf16* l) {
  __builtin_amdgcn_global_load_lds(
      (const __attribute__((address_space(1))) unsigned int*)g,
      (__attribute__((address_space(3))) unsigned int*)l, 16, 0, 0);
}

// converted-weights element offsets inside wb
#define OFF_X      0L
#define OFF_INW    1048576L            // [2] x 4194304
#define OFF_XPROJ  9437184L            // [2] x 196608
#define OFF_DTW    9830400L            // [2] x 131072
#define OFF_OUTW   10092544L           // [2] x 2097152
#define OFF_PROJW  14286848L           // 2097152
#define CVT_TOTAL  16384000L

// ---------------------------------------------------------------------------
// fp32 -> bf16 conversion of x + all GEMM weights into wb (16.384M elems)
// ---------------------------------------------------------------------------
__global__ __launch_bounds__(256) void cvt_k(
    const float* __restrict__ x,
    const float* __restrict__ inw0, const float* __restrict__ inw1,
    const float* __restrict__ xp0,  const float* __restrict__ xp1,
    const float* __restrict__ dt0,  const float* __restrict__ dt1,
    const float* __restrict__ ow0,  const float* __restrict__ ow1,
    const float* __restrict__ pw,   bf16* __restrict__ wb)
{
  long i = ((long)blockIdx.x * 256 + threadIdx.x) * 8;
  if (i >= CVT_TOTAL) return;
  const float* src; long off;
  if      (i < OFF_INW)                 { src = x;    off = i - OFF_X; }
  else if (i < OFF_INW + 4194304L)      { src = inw0; off = i - OFF_INW; }
  else if (i < OFF_XPROJ)               { src = inw1; off = i - (OFF_INW + 4194304L); }
  else if (i < OFF_XPROJ + 196608L)     { src = xp0;  off = i - OFF_XPROJ; }
  else if (i < OFF_DTW)                 { src = xp1;  off = i - (OFF_XPROJ + 196608L); }
  else if (i < OFF_DTW + 131072L)       { src = dt0;  off = i - OFF_DTW; }
  else if (i < OFF_OUTW)                { src = dt1;  off = i - (OFF_DTW + 131072L); }
  else if (i < OFF_OUTW + 2097152L)     { src = ow0;  off = i - OFF_OUTW; }
  else if (i < OFF_PROJW)               { src = ow1;  off = i - (OFF_OUTW + 2097152L); }
  else                                  { src = pw;   off = i - OFF_PROJW; }
  f32x4 v0 = *(const f32x4*)(src + off);
  f32x4 v1 = *(const f32x4*)(src + off + 4);
  bf16x8 t;
  #pragma unroll
  for (int q = 0; q < 4; q++) { t[q] = (bf16)v0[q]; t[4+q] = (bf16)v1[q]; }
  *(bf16x8*)(wb + i) = t;
}

// ---------------------------------------------------------------------------
// All-bf16 MFMA GEMM, B^T layout: C[m][n] = sum_k A[m][k] * B[n][k]
// Templated tile BMxBN (BK=64), 256 threads = 2x2 waves. global_load_lds
// staging, XOR-8 swizzle (conflict-free, verified R7/R8).
// splitN: columns >= splitN go to Cv2 (dense split of xi|z for in-proj).
// fuseRes=1: fused[row][z*DM+gn] = v + xF[row][gn], row = z ? M-1-gm : gm.
// ---------------------------------------------------------------------------
template<int BM, int BN>
__global__ __launch_bounds__(256) void gemm_bt(
    const bf16* __restrict__ A, const bf16* __restrict__ B0, const bf16* __restrict__ B1,
    void* __restrict__ Cv, void* __restrict__ Cv2, int splitN,
    int M, int N, int K, int lda, int ldb, int ldc,
    long aOffZ, long cOffZ,
    const float* __restrict__ bias0, const float* __restrict__ bias1,
    int flipA1, int writeBf16, int act,
    const float* __restrict__ xF, int fuseRes)
{
  constexpr int WM = BM / 2, WN = BN / 2;
  constexpr int MI = WM / 16, NJ = WN / 16;
  constexpr int ACALLS = BM / 32;
  constexpr int BCALLS = BN / 32;

  const int tid  = threadIdx.x;
  const int z    = blockIdx.z;
  const bf16*  Bp   = z ? B1 : B0;
  const float* bias = z ? bias1 : bias0;
  const int flip = z ? flipA1 : 0;
  const int bm = blockIdx.x * BM;
  const int bn = blockIdx.y * BN;

  __shared__ bf16 As[BM * 64];
  __shared__ bf16 Bs[BN * 64];

  f32x4 acc[MI][NJ];
  #pragma unroll
  for (int i=0;i<MI;i++)
    #pragma unroll
    for (int j=0;j<NJ;j++) { acc[i][j][0]=0.f; acc[i][j][1]=0.f; acc[i][j][2]=0.f; acc[i][j][3]=0.f; }

  const int wave = tid >> 6;
  const int lane = tid & 63;
  const int wm = (wave >> 1) * WM;
  const int wn = (wave & 1) * WN;
  const int fr  = lane & 15;
  const int frx = fr & 7;
  const int kqc = lane >> 4;

  const bf16* aSrc[ACALLS];
  int aOff[ACALLS];
  #pragma unroll
  for (int t = 0; t < ACALLS; t++) {
    int s = (wave * ACALLS + t) * 64 + lane;
    int r = s >> 3;
    int j = (s & 7) ^ (r & 7);
    int ar = bm + r;
    int agr = flip ? (M - 1 - ar) : ar;
    aSrc[t] = A + (long)z * aOffZ + (long)agr * lda + j * 8;
    aOff[t] = (wave * ACALLS + t) * 512;
  }
  const bf16* bSrc[BCALLS];
  int bOff[BCALLS];
  #pragma unroll
  for (int t = 0; t < BCALLS; t++) {
    int s = (wave * BCALLS + t) * 64 + lane;
    int r = s >> 3;
    int j = (s & 7) ^ (r & 7);
    int br = bn + r; if (br > N - 1) br = N - 1;
    bSrc[t] = Bp + (long)br * ldb + j * 8;
    bOff[t] = (wave * BCALLS + t) * 512;
  }

  for (int k0 = 0; k0 < K; k0 += 64) {
    #pragma unroll
    for (int t = 0; t < ACALLS; t++) gl_lds16(aSrc[t] + k0, &As[aOff[t]]);
    #pragma unroll
    for (int t = 0; t < BCALLS; t++) gl_lds16(bSrc[t] + k0, &Bs[bOff[t]]);
    __syncthreads();

    #pragma unroll
    for (int ks8 = 0; ks8 < 8; ks8 += 4) {
      bf16x8 af[MI], bfr[NJ];
      #pragma unroll
      for (int i=0;i<MI;i++) {
        int row = wm + i*16 + fr;
        af[i]  = *(const bf16x8*)&As[(row * 8 + ((ks8 + kqc) ^ frx)) * 8];
      }
      #pragma unroll
      for (int j=0;j<NJ;j++) {
        int row = wn + j*16 + fr;
        bfr[j] = *(const bf16x8*)&Bs[(row * 8 + ((ks8 + kqc) ^ frx)) * 8];
      }
      #pragma unroll
      for (int i=0;i<MI;i++)
        #pragma unroll
        for (int j=0;j<NJ;j++)
          acc[i][j] = __builtin_amdgcn_mfma_f32_16x16x32_bf16(af[i], bfr[j], acc[i][j], 0, 0, 0);
    }
    __syncthreads();
  }

  const int rr = (lane >> 4) * 4;
  const int cc = lane & 15;
  #pragma unroll
  for (int i=0;i<MI;i++) {
    #pragma unroll
    for (int j=0;j<NJ;j++) {
      int gn = bn + wn + j*16 + cc;
      if (gn >= N) continue;
      float bv = bias ? bias[gn] : 0.f;
      #pragma unroll
      for (int r=0;r<4;r++) {
        int gm = bm + wm + i*16 + rr + r;
        float v = acc[i][j][r] + bv;
        if (fuseRes) {
          long row = z ? (long)(M - 1 - gm) : (long)gm;
          float o = v + xF[row * DM + gn];
          ((bf16*)Cv)[row * (2 * DM) + (long)z * DM + gn] = f2bf(o);
        } else {
          // cheap softplus: max(v,0) + log(1+exp(-|v|)) via fast intrinsics
          if (act == 1) v = fmaxf(v, 0.f) + __logf(1.f + __expf(-fabsf(v)));
          int gn2 = gn;
          void* Cp = Cv;
          if (gn >= splitN) { gn2 = gn - splitN; Cp = Cv2; }
          long idx = (long)z * cOffZ + (long)gm * ldc + gn2;
          if (writeBf16) ((bf16*)Cp)[idx] = f2bf(v);
          else           ((float*)Cp)[idx] = v;
        }
      }
    }
  }
}

// ---------------------------------------------------------------------------
// Fused conv+silu+xproj GEMM: xdbl = u @ xproj_w^T, u = silu(conv(xi)+cb),
// computed on the fly during A-staging; u also written to global (y==0 blocks)
// for the scan kernels. BM=32, BN=64, K=DI. A-tile k-dim = channel d.
// ---------------------------------------------------------------------------
__global__ __launch_bounds__(256) void gemm_xproj_conv(
    const bf16* __restrict__ xi, const bf16* __restrict__ B0, const bf16* __restrict__ B1,
    const float* __restrict__ cw0, const float* __restrict__ cw1,
    const float* __restrict__ cb0, const float* __restrict__ cb1,
    bf16* __restrict__ xdbl, bf16* __restrict__ u)
{
  constexpr int BM = 32, BN = 64, NB = 96;
  const int tid = threadIdx.x;
  const int z   = blockIdx.z;
  const bf16* Bp  = z ? B1 : B0;
  const float* cw = z ? cw1 : cw0;
  const float* cb = z ? cb1 : cb0;
  const bf16* xid = xi + (long)z * L_SEQ * DI;
  bf16* ud        = u  + (long)z * L_SEQ * DI;
  const int bm = blockIdx.x * BM;
  const int bn = blockIdx.y * BN;

  __shared__ bf16 As[BM * 64];
  __shared__ bf16 Bs[BN * 64];

  f32x4 acc[1][2];
  acc[0][0][0]=0.f; acc[0][0][1]=0.f; acc[0][0][2]=0.f; acc[0][0][3]=0.f;
  acc[0][1] = acc[0][0];

  const int wave = tid >> 6;
  const int lane = tid & 63;
  const int wm = (wave >> 1) * 16;
  const int wn = (wave & 1) * 32;
  const int fr  = lane & 15;
  const int frx = fr & 7;
  const int kqc = lane >> 4;

  // A staging geometry: thread -> (row r, col chunk) of the 32x64 u-tile
  const int ar  = tid >> 3;          // 0..31
  const int ac0 = (tid & 7) * 8;     // 0..56
  const int al  = bm + ar;           // absolute l
  const int aswz = ((ac0 >> 3) ^ (ar & 7)) * 8 + ar * 64;  // LDS elem offset
  const bool writeU = (blockIdx.y == 0);

  // B staging (gl_lds, row clamp for N=96 edge)
  const bf16* bSrc[2];
  int bOff[2];
  #pragma unroll
  for (int t = 0; t < 2; t++) {
    int s = (wave * 2 + t) * 64 + lane;
    int r = s >> 3;
    int j = (s & 7) ^ (r & 7);
    int br = bn + r; if (br > NB - 1) br = NB - 1;
    bSrc[t] = Bp + (long)br * DI + j * 8;
    bOff[t] = (wave * 2 + t) * 512;
  }

  for (int k0 = 0; k0 < DI; k0 += 64) {
    #pragma unroll
    for (int t = 0; t < 2; t++) gl_lds16(bSrc[t] + k0, &Bs[bOff[t]]);
    // compute u tile element-wise: d = k0 + ac0 + q
    {
      int d0 = k0 + ac0;
      float a[8];
      #pragma unroll
      for (int q = 0; q < 8; q++) a[q] = cb[d0 + q];
      f32x4 wq[8];
      #pragma unroll
      for (int q = 0; q < 8; q++) wq[q] = *(const f32x4*)(cw + (d0 + q) * 4);
      #pragma unroll
      for (int j = 0; j < 4; j++) {
        int ll = al - 3 + j;
        if (ll >= 0) {
          bf16x8 xv = *(const bf16x8*)(xid + (long)ll * DI + d0);
          #pragma unroll
          for (int q = 0; q < 8; q++) a[q] += wq[q][j] * bf2f(xv[q]);
        }
      }
      bf16x8 o;
      #pragma unroll
      for (int q = 0; q < 8; q++) {
        float s = a[q] / (1.f + __expf(-a[q]));
        o[q] = f2bf(s);
      }
      *(bf16x8*)&As[aswz] = o;
      if (writeU) *(bf16x8*)(ud + (long)al * DI + d0) = o;
    }
    __syncthreads();

    #pragma unroll
    for (int ks8 = 0; ks8 < 8; ks8 += 4) {
      bf16x8 af, bfr[2];
      af = *(const bf16x8*)&As[((wm + fr) * 8 + ((ks8 + kqc) ^ frx)) * 8];
      #pragma unroll
      for (int j = 0; j < 2; j++) {
        int row = wn + j * 16 + fr;
        bfr[j] = *(const bf16x8*)&Bs[(row * 8 + ((ks8 + kqc) ^ frx)) * 8];
      }
      acc[0][0] = __builtin_amdgcn_mfma_f32_16x16x32_bf16(af, bfr[0], acc[0][0], 0, 0, 0);
      acc[0][1] = __builtin_amdgcn_mfma_f32_16x16x32_bf16(af, bfr[1], acc[0][1], 0, 0, 0);
    }
    __syncthreads();
  }

  const int rr = (lane >> 4) * 4;
  const int cc = lane & 15;
  #pragma unroll
  for (int j = 0; j < 2; j++) {
    int gn = bn + wn + j * 16 + cc;
    if (gn >= NB) continue;
    #pragma unroll
    for (int r = 0; r < 4; r++) {
      int gm = bm + wm + rr + r;
      xdbl[(long)z * L_SEQ * XD + (long)gm * XD + gn] = f2bf(acc[0][j][r]);
    }
  }
}

// ---------------------------------------------------------------------------
// Chunk-parallel selective scan, 3 kernels (XCD-coherence via launch bounds).
// NC=64 chunks of CS=16; whole-chunk register preload (R9, verified).
// ---------------------------------------------------------------------------
__global__ __launch_bounds__(256) void scan_p1(
    const bf16* __restrict__ delta, const bf16* __restrict__ u, const bf16* __restrict__ xdbl,
    const float* __restrict__ Alog0, const float* __restrict__ Alog1,
    bf16* __restrict__ hout, float* __restrict__ sumd)
{
  const int tid = threadIdx.x;
  const int c   = blockIdx.y;
  const int dir = blockIdx.z;
  const int d   = blockIdx.x * 256 + tid;
  const float* Alog = dir ? Alog1 : Alog0;
  const bf16* dl = delta + (long)dir * L_SEQ * DI;
  const bf16* ud = u     + (long)dir * L_SEQ * DI;
  const bf16* xd = xdbl  + (long)dir * L_SEQ * XD;
  const int l0 = c * CS;

  __shared__ float lb[CS][16];
  {
    int ll = tid >> 4, n = tid & 15;
    lb[ll][n] = bf2f(xd[(long)(l0 + ll) * XD + DTR + n]);
  }

  float dl_r[CS], uu_r[CS];
  #pragma unroll
  for (int s = 0; s < CS; s++) {
    dl_r[s] = bf2f(dl[(long)(l0 + s) * DI + d]);
    uu_r[s] = bf2f(ud[(long)(l0 + s) * DI + d]);
  }
  __syncthreads();

  float An[16], h[16];
  #pragma unroll
  for (int n = 0; n < 16; n++) { An[n] = -__expf(Alog[d * 16 + n]); h[n] = 0.f; }
  float sd = 0.f;

  #pragma unroll
  for (int ll = 0; ll < CS; ll++) {
    float dlt = dl_r[ll];
    sd += dlt;
    float du = dlt * uu_r[ll];
    #pragma unroll
    for (int n = 0; n < 16; n++) {
      float a = __expf(dlt * An[n]);
      h[n] = h[n] * a + du * lb[ll][n];
    }
  }

  bf16* hp = hout + (((long)dir * NC + c) * DI + d) * 16;
  bf16x8 o0, o1;
  #pragma unroll
  for (int n = 0; n < 8; n++) { o0[n] = f2bf(h[n]); o1[n] = f2bf(h[8 + n]); }
  *(bf16x8*)hp = o0;
  *(bf16x8*)(hp + 8) = o1;
  sumd[((long)dir * NC + c) * DI + d] = sd;
}

__global__ __launch_bounds__(256) void scan_p2(
    const float* __restrict__ Alog0, const float* __restrict__ Alog1,
    bf16* hout, const float* __restrict__ sumd)
{
  int g = blockIdx.x * 256 + threadIdx.x;   // 2*2048*16 = 65536
  int dir = g >> 15;
  int rem = g & 32767;
  int d = rem >> 4;
  int n = rem & 15;
  const float* Alog = dir ? Alog1 : Alog0;
  float An = -__expf(Alog[d * 16 + n]);
  float hs = 0.f;
  #pragma unroll 4
  for (int c = 0; c < NC; c++) {
    long base = ((long)dir * NC + c) * DI + d;
    float tmp = bf2f(hout[base * 16 + n]);
    float P = __expf(An * sumd[base]);
    hout[base * 16 + n] = f2bf(hs);   // h_start for chunk c
    hs = P * hs + tmp;
  }
}

__global__ __launch_bounds__(256) void scan_p3(
    const bf16* delta, const bf16* zb, const bf16* u, const bf16* __restrict__ xdbl,
    const float* __restrict__ Alog0, const float* __restrict__ Alog1,
    const float* __restrict__ Dp0, const float* __restrict__ Dp1,
    const bf16* __restrict__ hout, bf16* g)
{
  const int tid = threadIdx.x;
  const int c   = blockIdx.y;
  const int dir = blockIdx.z;
  const int d   = blockIdx.x * 256 + tid;
  const float* Alog = dir ? Alog1 : Alog0;
  const float* Dp   = dir ? Dp1 : Dp0;
  const bf16* dl = delta + (long)dir * L_SEQ * DI;
  const bf16* zd = zb    + (long)dir * L_SEQ * DI;
  const bf16* ud = u     + (long)dir * L_SEQ * DI;
  const bf16* xd = xdbl  + (long)dir * L_SEQ * XD;
  bf16* gd = g + (long)dir * L_SEQ * DI;
  const int l0 = c * CS;

  __shared__ float lb[CS][16];
  __shared__ float lc[CS][16];
  {
    int i = tid * 2;
    int ll = i >> 5, j = i & 31;
    const bf16* p = xd + (long)(l0 + ll) * XD + DTR + j;
    float v0 = bf2f(p[0]), v1 = bf2f(p[1]);
    if (j < 16) { lb[ll][j] = v0; lb[ll][j + 1] = v1; }
    else        { lc[ll][j - 16] = v0; lc[ll][j - 15] = v1; }
  }

  float dl_r[CS], uu_r[CS], zv_r[CS];
  #pragma unroll
  for (int s = 0; s < CS; s++) {
    dl_r[s] = bf2f(dl[(long)(l0 + s) * DI + d]);
    zv_r[s] = bf2f(zd[(long)(l0 + s) * DI + d]);
    uu_r[s] = bf2f(ud[(long)(l0 + s) * DI + d]);
  }
  const bf16* hp = hout + (((long)dir * NC + c) * DI + d) * 16;
  bf16x8 h0 = *(const bf16x8*)hp;
  bf16x8 h1 = *(const bf16x8*)(hp + 8);
  __syncthreads();

  float An[16], h[16];
  #pragma unroll
  for (int n = 0; n < 16; n++) {
    An[n] = -__expf(Alog[d * 16 + n]);
    h[n] = bf2f(n < 8 ? h0[n & 7] : h1[n & 7]);
  }
  const float Dpv = Dp[d];

  #pragma unroll
  for (int ll = 0; ll < CS; ll++) {
    float dlt = dl_r[ll];
    float du = dlt * uu_r[ll];
    float y = 0.f;
    #pragma unroll
    for (int n = 0; n < 16; n++) {
      float a = __expf(dlt * An[n]);
      h[n] = h[n] * a + du * lb[ll][n];
      y += h[n] * lc[ll][n];
    }
    y += uu_r[ll] * Dpv;
    float zv = zv_r[ll];
    float sz = zv / (1.f + __expf(-zv));
    gd[(long)(l0 + ll) * DI + d] = f2bf(y * sz);
  }
}

// ---------------------------------------------------------------------------
// +proj_b then LayerNorm over last dim (1024), write fp32 out
// ---------------------------------------------------------------------------
__global__ __launch_bounds__(256) void ln_k(
    const float* __restrict__ fin, const float* __restrict__ pb,
    const float* __restrict__ lnw, const float* __restrict__ lnb, float* __restrict__ out)
{
  int row = blockIdx.x;
  int tid = threadIdx.x;
  float v[4]; float s1 = 0.f, s2 = 0.f;
  #pragma unroll
  for (int j = 0; j < 4; j++) {
    int c = tid + j * 256;
    v[j] = fin[(long)row * DM + c] + pb[c];
    s1 += v[j]; s2 += v[j] * v[j];
  }
  #pragma unroll
  for (int off = 32; off; off >>= 1) { s1 += __shfl_down(s1, off); s2 += __shfl_down(s2, off); }
  __shared__ float red[8];
  int wave = tid >> 6, lane = tid & 63;
  if (lane == 0) { red[wave] = s1; red[4 + wave] = s2; }
  __syncthreads();
  float t1 = red[0] + red[1] + red[2] + red[3];
  float t2 = red[4] + red[5] + red[6] + red[7];
  float mu = t1 / DM;
  float var = t2 / DM - mu * mu;
  float inv = rsqrtf(var + 1e-5f);
  #pragma unroll
  for (int j = 0; j < 4; j++) {
    int c = tid + j * 256;
    out[(long)row * DM + c] = (v[j] - mu) * inv * lnw[c] + lnb[c];
  }
}

// ---------------------------------------------------------------------------
extern "C" void kernel_launch(void* const* d_in, const int* in_sizes, int n_in,
                              void* d_out, int out_size, void* d_ws, size_t ws_size,
                              hipStream_t stream)
{
  const float* x         = (const float*)d_in[0];
  const float* fw_conv_w = (const float*)d_in[2];
  const float* fw_conv_b = (const float*)d_in[3];
  const float* fw_dt_b   = (const float*)d_in[6];
  const float* fw_Alog   = (const float*)d_in[7];
  const float* fw_Dp     = (const float*)d_in[8];
  const float* bw_conv_w = (const float*)d_in[11];
  const float* bw_conv_b = (const float*)d_in[12];
  const float* bw_dt_b   = (const float*)d_in[15];
  const float* bw_Alog   = (const float*)d_in[16];
  const float* bw_Dp     = (const float*)d_in[17];
  const float* proj_b    = (const float*)d_in[20];
  const float* ln_w      = (const float*)d_in[21];
  const float* ln_b      = (const float*)d_in[22];

  // workspace layout (peak ~65.3 MB, same as R10):
  //   xi bf16 [2][1024][2048] @ 0..8MB   (delta overwrites in place after xproj)
  //   zb bf16 [2][1024][2048] @ 8..16MB
  //   u/g bf16 [2][1024][2048] @ 16..24MB (g in-place over u)
  //   xdbl bf16 [2][1024][96] @ 24..24.4MB
  //   sumd f32 [2][64][2048]  @ 25..26MB
  //   hout bf16 [2][64][2048][16] @ 26..34MB
  //   wb bf16 (converted x + weights) @ 34..65.3MB
  //   phase 2 (over dead xi): fused bf16 [1024][2048] @0..4MB, fin f32 @4..8MB
  char* ws = (char*)d_ws;
  const size_t MB = 1024 * 1024;
  bf16*  xi    = (bf16*)(ws + 0);
  bf16*  zb    = (bf16*)(ws + 8 * MB);
  bf16*  u     = (bf16*)(ws + 16 * MB);
  bf16*  xdbl  = (bf16*)(ws + 24 * MB);
  float* sumd  = (float*)(ws + 25 * MB);
  bf16*  hout  = (bf16*)(ws + 26 * MB);
  bf16*  wb    = (bf16*)(ws + 34 * MB);
  bf16*  g     = u;
  bf16*  delta = xi;                      // dense, in place over dead xi
  bf16*  fused = (bf16*)(ws + 0);
  float* fin   = (float*)(ws + 4 * MB);

  bf16* xb     = wb + OFF_X;
  bf16* inw    = wb + OFF_INW;     // [2][4096][1024]
  bf16* xprojw = wb + OFF_XPROJ;   // [2][96][2048]
  bf16* dtw    = wb + OFF_DTW;     // [2][2048][64]
  bf16* outw   = wb + OFF_OUTW;    // [2][1024][2048]
  bf16* projw  = wb + OFF_PROJW;   // [1024][2048]

  dim3 blk(256);
  const int BIGN = 1 << 30;

  // 0. convert x + weights to bf16
  cvt_k<<<(CVT_TOTAL / 8 + 255) / 256, blk, 0, stream>>>(
      x, (const float*)d_in[1], (const float*)d_in[10],
      (const float*)d_in[4], (const float*)d_in[13],
      (const float*)d_in[5], (const float*)d_in[14],
      (const float*)d_in[9], (const float*)d_in[18],
      (const float*)d_in[19], wb);

  // 1. in-proj: [xi|z][dir] = (flip?)xb @ in_w^T, split-written dense (64x64 tiles)
  gemm_bt<64,64><<<dim3(16, 64, 2), blk, 0, stream>>>(
      xb, inw, inw + 4194304L, (void*)xi, (void*)zb, 2048,
      1024, 4096, 1024, 1024, 1024, 2048,
      0L, (long)1024 * 2048, nullptr, nullptr, 1, 1, 0, nullptr, 0);

  // 2. fused conv+silu+xproj: u computed during A-staging; xdbl = u @ xproj_w^T
  gemm_xproj_conv<<<dim3(32, 2, 2), blk, 0, stream>>>(
      xi, xprojw, xprojw + 196608L,
      fw_conv_w, bw_conv_w, fw_conv_b, bw_conv_b, xdbl, u);

  // 3. delta = softplus(dt @ dt_w^T + dt_b) -> dense over dead xi (ldc=2048)
  gemm_bt<32,64><<<dim3(32, 32, 2), blk, 0, stream>>>(
      xdbl, dtw, dtw + 131072L, (void*)delta, nullptr, BIGN,
      1024, 2048, 64, 96, 64, 2048,
      (long)1024 * 96, (long)1024 * 2048, fw_dt_b, bw_dt_b, 0, 1, 1, nullptr, 0);

  // 4. chunk-parallel scan: p1 local -> p2 combine -> p3 rescan+gate
  scan_p1<<<dim3(8, NC, 2), blk, 0, stream>>>(delta, u, xdbl, fw_Alog, bw_Alog, hout, sumd);
  scan_p2<<<dim3(256), blk, 0, stream>>>(fw_Alog, bw_Alog, hout, sumd);
  scan_p3<<<dim3(8, NC, 2), blk, 0, stream>>>(delta, zb, u, xdbl, fw_Alog, bw_Alog,
                                              fw_Dp, bw_Dp, hout, g);

  // 5. out-proj + residual + unflip + concat -> fused (bf16 [1024][2048])
  gemm_bt<32,64><<<dim3(32, 16, 2), blk, 0, stream>>>(
      g, outw, outw + 2097152L, (void*)fused, nullptr, BIGN,
      1024, 1024, 2048, 2048, 2048, 1024,
      (long)1024 * 2048, 0L, nullptr, nullptr, 0, 1, 0, x, 1);

  // 6. final proj: fin = fused @ proj_w^T (fp32 out)
  gemm_bt<32,64><<<dim3(32, 16, 1), blk, 0, stream>>>(
      fused, projw, projw, (void*)fin, nullptr, BIGN,
      1024, 1024, 2048, 2048, 2048, 1024,
      0L, 0L, nullptr, nullptr, 0, 0, 0, nullptr, 0);

  // 7. +proj_b, LayerNorm -> d_out (fp32)
  ln_k<<<1024, blk, 0, stream>>>(fin, proj_b, ln_w, ln_b, (float*)d_out);
}

// Round 12
// 327.459 us; speedup vs baseline: 1.0903x; 1.0903x over previous
//
#include <hip/hip_runtime.h>

typedef __bf16 bf16;
typedef __bf16 bf16x8 __attribute__((ext_vector_type(8)));
typedef float  f32x4  __attribute__((ext_vector_type(4)));

#define L_SEQ 1024
#define DM    1024
#define DI    2048
#define DTR   64
#define DSTATE 16
#define XD    96   // DT_RANK + 2*D_STATE
#define NC    64   // scan chunks
#define CS    16   // steps per chunk

__device__ __forceinline__ float bf2f(bf16 v){ return (float)v; }
__device__ __forceinline__ bf16  f2bf(float v){ return (bf16)v; }

// async global->LDS, 16B per lane; LDS dest = wave-uniform base + lane*16
__device__ __forceinline__ void gl_lds16(const bf16* g, bf16* l) {
  __builtin_amdgcn_global_load_lds(
      (const __attribute__((address_space(1))) unsigned int*)g,
      (__attribute__((address_space(3))) unsigned int*)l, 16, 0, 0);
}

// converted-weights element offsets inside wb
#define OFF_X      0L
#define OFF_INW    1048576L            // [2] x 4194304
#define OFF_XPROJ  9437184L            // [2] x 196608
#define OFF_DTW    9830400L            // [2] x 131072
#define OFF_OUTW   10092544L           // [2] x 2097152
#define OFF_PROJW  14286848L           // 2097152
#define CVT_TOTAL  16384000L

// ---------------------------------------------------------------------------
// fp32 -> bf16 conversion of x + all GEMM weights into wb (16.384M elems)
// ---------------------------------------------------------------------------
__global__ __launch_bounds__(256) void cvt_k(
    const float* __restrict__ x,
    const float* __restrict__ inw0, const float* __restrict__ inw1,
    const float* __restrict__ xp0,  const float* __restrict__ xp1,
    const float* __restrict__ dt0,  const float* __restrict__ dt1,
    const float* __restrict__ ow0,  const float* __restrict__ ow1,
    const float* __restrict__ pw,   bf16* __restrict__ wb)
{
  long i = ((long)blockIdx.x * 256 + threadIdx.x) * 8;
  if (i >= CVT_TOTAL) return;
  const float* src; long off;
  if      (i < OFF_INW)                 { src = x;    off = i - OFF_X; }
  else if (i < OFF_INW + 4194304L)      { src = inw0; off = i - OFF_INW; }
  else if (i < OFF_XPROJ)               { src = inw1; off = i - (OFF_INW + 4194304L); }
  else if (i < OFF_XPROJ + 196608L)     { src = xp0;  off = i - OFF_XPROJ; }
  else if (i < OFF_DTW)                 { src = xp1;  off = i - (OFF_XPROJ + 196608L); }
  else if (i < OFF_DTW + 131072L)       { src = dt0;  off = i - OFF_DTW; }
  else if (i < OFF_OUTW)                { src = dt1;  off = i - (OFF_DTW + 131072L); }
  else if (i < OFF_OUTW + 2097152L)     { src = ow0;  off = i - OFF_OUTW; }
  else if (i < OFF_PROJW)               { src = ow1;  off = i - (OFF_OUTW + 2097152L); }
  else                                  { src = pw;   off = i - OFF_PROJW; }
  f32x4 v0 = *(const f32x4*)(src + off);
  f32x4 v1 = *(const f32x4*)(src + off + 4);
  bf16x8 t;
  #pragma unroll
  for (int q = 0; q < 4; q++) { t[q] = (bf16)v0[q]; t[4+q] = (bf16)v1[q]; }
  *(bf16x8*)(wb + i) = t;
}

// ---------------------------------------------------------------------------
// All-bf16 MFMA GEMM, B^T layout: C[m][n] = sum_k A[m][k] * B[n][k]
// Templated tile BMxBN (BK=64), 256 threads = 2x2 waves. global_load_lds
// staging, XOR-8 swizzle (conflict-free, verified R7/R8).
// splitN: columns >= splitN go to Cv2 (dense split of xi|z for in-proj).
// fuseRes=1: fused[row][z*DM+gn] = v + xF[row][gn], row = z ? M-1-gm : gm.
// ---------------------------------------------------------------------------
template<int BM, int BN>
__global__ __launch_bounds__(256) void gemm_bt(
    const bf16* __restrict__ A, const bf16* __restrict__ B0, const bf16* __restrict__ B1,
    void* __restrict__ Cv, void* __restrict__ Cv2, int splitN,
    int M, int N, int K, int lda, int ldb, int ldc,
    long aOffZ, long cOffZ,
    const float* __restrict__ bias0, const float* __restrict__ bias1,
    int flipA1, int writeBf16, int act,
    const float* __restrict__ xF, int fuseRes)
{
  constexpr int WM = BM / 2, WN = BN / 2;
  constexpr int MI = WM / 16, NJ = WN / 16;
  constexpr int ACALLS = BM / 32;
  constexpr int BCALLS = BN / 32;

  const int tid  = threadIdx.x;
  const int z    = blockIdx.z;
  const bf16*  Bp   = z ? B1 : B0;
  const float* bias = z ? bias1 : bias0;
  const int flip = z ? flipA1 : 0;
  const int bm = blockIdx.x * BM;
  const int bn = blockIdx.y * BN;

  __shared__ bf16 As[BM * 64];
  __shared__ bf16 Bs[BN * 64];

  f32x4 acc[MI][NJ];
  #pragma unroll
  for (int i=0;i<MI;i++)
    #pragma unroll
    for (int j=0;j<NJ;j++) { acc[i][j][0]=0.f; acc[i][j][1]=0.f; acc[i][j][2]=0.f; acc[i][j][3]=0.f; }

  const int wave = tid >> 6;
  const int lane = tid & 63;
  const int wm = (wave >> 1) * WM;
  const int wn = (wave & 1) * WN;
  const int fr  = lane & 15;
  const int frx = fr & 7;
  const int kqc = lane >> 4;

  const bf16* aSrc[ACALLS];
  int aOff[ACALLS];
  #pragma unroll
  for (int t = 0; t < ACALLS; t++) {
    int s = (wave * ACALLS + t) * 64 + lane;
    int r = s >> 3;
    int j = (s & 7) ^ (r & 7);
    int ar = bm + r;
    int agr = flip ? (M - 1 - ar) : ar;
    aSrc[t] = A + (long)z * aOffZ + (long)agr * lda + j * 8;
    aOff[t] = (wave * ACALLS + t) * 512;
  }
  const bf16* bSrc[BCALLS];
  int bOff[BCALLS];
  #pragma unroll
  for (int t = 0; t < BCALLS; t++) {
    int s = (wave * BCALLS + t) * 64 + lane;
    int r = s >> 3;
    int j = (s & 7) ^ (r & 7);
    int br = bn + r; if (br > N - 1) br = N - 1;
    bSrc[t] = Bp + (long)br * ldb + j * 8;
    bOff[t] = (wave * BCALLS + t) * 512;
  }

  for (int k0 = 0; k0 < K; k0 += 64) {
    #pragma unroll
    for (int t = 0; t < ACALLS; t++) gl_lds16(aSrc[t] + k0, &As[aOff[t]]);
    #pragma unroll
    for (int t = 0; t < BCALLS; t++) gl_lds16(bSrc[t] + k0, &Bs[bOff[t]]);
    __syncthreads();

    #pragma unroll
    for (int ks8 = 0; ks8 < 8; ks8 += 4) {
      bf16x8 af[MI], bfr[NJ];
      #pragma unroll
      for (int i=0;i<MI;i++) {
        int row = wm + i*16 + fr;
        af[i]  = *(const bf16x8*)&As[(row * 8 + ((ks8 + kqc) ^ frx)) * 8];
      }
      #pragma unroll
      for (int j=0;j<NJ;j++) {
        int row = wn + j*16 + fr;
        bfr[j] = *(const bf16x8*)&Bs[(row * 8 + ((ks8 + kqc) ^ frx)) * 8];
      }
      #pragma unroll
      for (int i=0;i<MI;i++)
        #pragma unroll
        for (int j=0;j<NJ;j++)
          acc[i][j] = __builtin_amdgcn_mfma_f32_16x16x32_bf16(af[i], bfr[j], acc[i][j], 0, 0, 0);
    }
    __syncthreads();
  }

  const int rr = (lane >> 4) * 4;
  const int cc = lane & 15;
  #pragma unroll
  for (int i=0;i<MI;i++) {
    #pragma unroll
    for (int j=0;j<NJ;j++) {
      int gn = bn + wn + j*16 + cc;
      if (gn >= N) continue;
      float bv = bias ? bias[gn] : 0.f;
      #pragma unroll
      for (int r=0;r<4;r++) {
        int gm = bm + wm + i*16 + rr + r;
        float v = acc[i][j][r] + bv;
        if (fuseRes) {
          long row = z ? (long)(M - 1 - gm) : (long)gm;
          float o = v + xF[row * DM + gn];
          ((bf16*)Cv)[row * (2 * DM) + (long)z * DM + gn] = f2bf(o);
        } else {
          // cheap softplus: max(v,0) + log(1+exp(-|v|)) via fast intrinsics
          if (act == 1) v = fmaxf(v, 0.f) + __logf(1.f + __expf(-fabsf(v)));
          int gn2 = gn;
          void* Cp = Cv;
          if (gn >= splitN) { gn2 = gn - splitN; Cp = Cv2; }
          long idx = (long)z * cOffZ + (long)gm * ldc + gn2;
          if (writeBf16) ((bf16*)Cp)[idx] = f2bf(v);
          else           ((float*)Cp)[idx] = v;
        }
      }
    }
  }
}

// ---------------------------------------------------------------------------
// depthwise causal conv(4) + bias + silu : u[dir][l][d], 8 channels/thread
// reads dense xi buffer [dir][l][DI]
// ---------------------------------------------------------------------------
__global__ __launch_bounds__(256) void conv_silu_k(
    const bf16* __restrict__ xi, const float* __restrict__ cw0, const float* __restrict__ cw1,
    const float* __restrict__ cb0, const float* __restrict__ cb1, bf16* __restrict__ u)
{
  int gid = blockIdx.x * 256 + threadIdx.x;     // over 2*L*DI/8 = 524288
  int dir = gid >> 18;
  int rem = gid & ((1 << 18) - 1);
  int l = rem >> 8;
  int d0 = (rem & 255) * 8;
  const float* w = dir ? cw1 : cw0;
  const float* b = dir ? cb1 : cb0;
  const bf16* xid = xi + (long)dir * L_SEQ * DI;
  float acc[8];
  #pragma unroll
  for (int q = 0; q < 8; q++) acc[q] = b[d0 + q];
  #pragma unroll
  for (int j = 0; j < 4; j++) {
    int ll = l - 3 + j;
    if (ll < 0) continue;
    bf16x8 xv = *(const bf16x8*)(xid + (long)ll * DI + d0);
    #pragma unroll
    for (int q = 0; q < 8; q++) acc[q] += w[(d0 + q) * 4 + j] * bf2f(xv[q]);
  }
  bf16x8 o;
  #pragma unroll
  for (int q = 0; q < 8; q++) {
    float s = acc[q] / (1.f + __expf(-acc[q]));
    o[q] = f2bf(s);
  }
  *(bf16x8*)(u + (long)dir * L_SEQ * DI + (long)l * DI + d0) = o;
}

// ---------------------------------------------------------------------------
// Chunk-parallel selective scan, 3 kernels (XCD-coherence via launch bounds).
// NC=64 chunks of CS=16; whole-chunk register preload (R9, verified).
// ---------------------------------------------------------------------------
__global__ __launch_bounds__(256) void scan_p1(
    const bf16* __restrict__ delta, const bf16* __restrict__ u, const bf16* __restrict__ xdbl,
    const float* __restrict__ Alog0, const float* __restrict__ Alog1,
    bf16* __restrict__ hout, float* __restrict__ sumd)
{
  const int tid = threadIdx.x;
  const int c   = blockIdx.y;
  const int dir = blockIdx.z;
  const int d   = blockIdx.x * 256 + tid;
  const float* Alog = dir ? Alog1 : Alog0;
  const bf16* dl = delta + (long)dir * L_SEQ * DI;
  const bf16* ud = u     + (long)dir * L_SEQ * DI;
  const bf16* xd = xdbl  + (long)dir * L_SEQ * XD;
  const int l0 = c * CS;

  __shared__ float lb[CS][16];
  {
    int ll = tid >> 4, n = tid & 15;
    lb[ll][n] = bf2f(xd[(long)(l0 + ll) * XD + DTR + n]);
  }

  float dl_r[CS], uu_r[CS];
  #pragma unroll
  for (int s = 0; s < CS; s++) {
    dl_r[s] = bf2f(dl[(long)(l0 + s) * DI + d]);
    uu_r[s] = bf2f(ud[(long)(l0 + s) * DI + d]);
  }
  __syncthreads();

  float An[16], h[16];
  #pragma unroll
  for (int n = 0; n < 16; n++) { An[n] = -__expf(Alog[d * 16 + n]); h[n] = 0.f; }
  float sd = 0.f;

  #pragma unroll
  for (int ll = 0; ll < CS; ll++) {
    float dlt = dl_r[ll];
    sd += dlt;
    float du = dlt * uu_r[ll];
    #pragma unroll
    for (int n = 0; n < 16; n++) {
      float a = __expf(dlt * An[n]);
      h[n] = h[n] * a + du * lb[ll][n];
    }
  }

  bf16* hp = hout + (((long)dir * NC + c) * DI + d) * 16;
  bf16x8 o0, o1;
  #pragma unroll
  for (int n = 0; n < 8; n++) { o0[n] = f2bf(h[n]); o1[n] = f2bf(h[8 + n]); }
  *(bf16x8*)hp = o0;
  *(bf16x8*)(hp + 8) = o1;
  sumd[((long)dir * NC + c) * DI + d] = sd;
}

__global__ __launch_bounds__(256) void scan_p2(
    const float* __restrict__ Alog0, const float* __restrict__ Alog1,
    bf16* hout, const float* __restrict__ sumd)
{
  int g = blockIdx.x * 256 + threadIdx.x;   // 2*2048*16 = 65536
  int dir = g >> 15;
  int rem = g & 32767;
  int d = rem >> 4;
  int n = rem & 15;
  const float* Alog = dir ? Alog1 : Alog0;
  float An = -__expf(Alog[d * 16 + n]);
  float hs = 0.f;
  #pragma unroll 4
  for (int c = 0; c < NC; c++) {
    long base = ((long)dir * NC + c) * DI + d;
    float tmp = bf2f(hout[base * 16 + n]);
    float P = __expf(An * sumd[base]);
    hout[base * 16 + n] = f2bf(hs);   // h_start for chunk c
    hs = P * hs + tmp;
  }
}

__global__ __launch_bounds__(256) void scan_p3(
    const bf16* delta, const bf16* zb, const bf16* u, const bf16* __restrict__ xdbl,
    const float* __restrict__ Alog0, const float* __restrict__ Alog1,
    const float* __restrict__ Dp0, const float* __restrict__ Dp1,
    const bf16* __restrict__ hout, bf16* g)
{
  const int tid = threadIdx.x;
  const int c   = blockIdx.y;
  const int dir = blockIdx.z;
  const int d   = blockIdx.x * 256 + tid;
  const float* Alog = dir ? Alog1 : Alog0;
  const float* Dp   = dir ? Dp1 : Dp0;
  const bf16* dl = delta + (long)dir * L_SEQ * DI;
  const bf16* zd = zb    + (long)dir * L_SEQ * DI;
  const bf16* ud = u     + (long)dir * L_SEQ * DI;
  const bf16* xd = xdbl  + (long)dir * L_SEQ * XD;
  bf16* gd = g + (long)dir * L_SEQ * DI;
  const int l0 = c * CS;

  __shared__ float lb[CS][16];
  __shared__ float lc[CS][16];
  {
    int i = tid * 2;
    int ll = i >> 5, j = i & 31;
    const bf16* p = xd + (long)(l0 + ll) * XD + DTR + j;
    float v0 = bf2f(p[0]), v1 = bf2f(p[1]);
    if (j < 16) { lb[ll][j] = v0; lb[ll][j + 1] = v1; }
    else        { lc[ll][j - 16] = v0; lc[ll][j - 15] = v1; }
  }

  float dl_r[CS], uu_r[CS], zv_r[CS];
  #pragma unroll
  for (int s = 0; s < CS; s++) {
    dl_r[s] = bf2f(dl[(long)(l0 + s) * DI + d]);
    zv_r[s] = bf2f(zd[(long)(l0 + s) * DI + d]);
    uu_r[s] = bf2f(ud[(long)(l0 + s) * DI + d]);
  }
  const bf16* hp = hout + (((long)dir * NC + c) * DI + d) * 16;
  bf16x8 h0 = *(const bf16x8*)hp;
  bf16x8 h1 = *(const bf16x8*)(hp + 8);
  __syncthreads();

  float An[16], h[16];
  #pragma unroll
  for (int n = 0; n < 16; n++) {
    An[n] = -__expf(Alog[d * 16 + n]);
    h[n] = bf2f(n < 8 ? h0[n & 7] : h1[n & 7]);
  }
  const float Dpv = Dp[d];

  #pragma unroll
  for (int ll = 0; ll < CS; ll++) {
    float dlt = dl_r[ll];
    float du = dlt * uu_r[ll];
    float y = 0.f;
    #pragma unroll
    for (int n = 0; n < 16; n++) {
      float a = __expf(dlt * An[n]);
      h[n] = h[n] * a + du * lb[ll][n];
      y += h[n] * lc[ll][n];
    }
    y += uu_r[ll] * Dpv;
    float zv = zv_r[ll];
    float sz = zv / (1.f + __expf(-zv));
    gd[(long)(l0 + ll) * DI + d] = f2bf(y * sz);
  }
}

// ---------------------------------------------------------------------------
// +proj_b then LayerNorm over last dim (1024), write fp32 out
// ---------------------------------------------------------------------------
__global__ __launch_bounds__(256) void ln_k(
    const float* __restrict__ fin, const float* __restrict__ pb,
    const float* __restrict__ lnw, const float* __restrict__ lnb, float* __restrict__ out)
{
  int row = blockIdx.x;
  int tid = threadIdx.x;
  float v[4]; float s1 = 0.f, s2 = 0.f;
  #pragma unroll
  for (int j = 0; j < 4; j++) {
    int c = tid + j * 256;
    v[j] = fin[(long)row * DM + c] + pb[c];
    s1 += v[j]; s2 += v[j] * v[j];
  }
  #pragma unroll
  for (int off = 32; off; off >>= 1) { s1 += __shfl_down(s1, off); s2 += __shfl_down(s2, off); }
  __shared__ float red[8];
  int wave = tid >> 6, lane = tid & 63;
  if (lane == 0) { red[wave] = s1; red[4 + wave] = s2; }
  __syncthreads();
  float t1 = red[0] + red[1] + red[2] + red[3];
  float t2 = red[4] + red[5] + red[6] + red[7];
  float mu = t1 / DM;
  float var = t2 / DM - mu * mu;
  float inv = rsqrtf(var + 1e-5f);
  #pragma unroll
  for (int j = 0; j < 4; j++) {
    int c = tid + j * 256;
    out[(long)row * DM + c] = (v[j] - mu) * inv * lnw[c] + lnb[c];
  }
}

// ---------------------------------------------------------------------------
extern "C" void kernel_launch(void* const* d_in, const int* in_sizes, int n_in,
                              void* d_out, int out_size, void* d_ws, size_t ws_size,
                              hipStream_t stream)
{
  const float* x         = (const float*)d_in[0];
  const float* fw_conv_w = (const float*)d_in[2];
  const float* fw_conv_b = (const float*)d_in[3];
  const float* fw_dt_b   = (const float*)d_in[6];
  const float* fw_Alog   = (const float*)d_in[7];
  const float* fw_Dp     = (const float*)d_in[8];
  const float* bw_conv_w = (const float*)d_in[11];
  const float* bw_conv_b = (const float*)d_in[12];
  const float* bw_dt_b   = (const float*)d_in[15];
  const float* bw_Alog   = (const float*)d_in[16];
  const float* bw_Dp     = (const float*)d_in[17];
  const float* proj_b    = (const float*)d_in[20];
  const float* ln_w      = (const float*)d_in[21];
  const float* ln_b      = (const float*)d_in[22];

  // workspace layout (peak ~65.3 MB, same as R10):
  //   xi bf16 [2][1024][2048] @ 0..8MB   (delta overwrites in place after conv)
  //   zb bf16 [2][1024][2048] @ 8..16MB
  //   u/g bf16 [2][1024][2048] @ 16..24MB (g in-place over u)
  //   xdbl bf16 [2][1024][96] @ 24..24.4MB
  //   sumd f32 [2][64][2048]  @ 25..26MB
  //   hout bf16 [2][64][2048][16] @ 26..34MB
  //   wb bf16 (converted x + weights) @ 34..65.3MB
  //   phase 2 (over dead xi): fused bf16 [1024][2048] @0..4MB, fin f32 @4..8MB
  char* ws = (char*)d_ws;
  const size_t MB = 1024 * 1024;
  bf16*  xi    = (bf16*)(ws + 0);
  bf16*  zb    = (bf16*)(ws + 8 * MB);
  bf16*  u     = (bf16*)(ws + 16 * MB);
  bf16*  xdbl  = (bf16*)(ws + 24 * MB);
  float* sumd  = (float*)(ws + 25 * MB);
  bf16*  hout  = (bf16*)(ws + 26 * MB);
  bf16*  wb    = (bf16*)(ws + 34 * MB);
  bf16*  g     = u;
  bf16*  delta = xi;                      // dense, in place over dead xi
  bf16*  fused = (bf16*)(ws + 0);
  float* fin   = (float*)(ws + 4 * MB);

  bf16* xb     = wb + OFF_X;
  bf16* inw    = wb + OFF_INW;     // [2][4096][1024]
  bf16* xprojw = wb + OFF_XPROJ;   // [2][96][2048]
  bf16* dtw    = wb + OFF_DTW;     // [2][2048][64]
  bf16* outw   = wb + OFF_OUTW;    // [2][1024][2048]
  bf16* projw  = wb + OFF_PROJW;   // [1024][2048]

  dim3 blk(256);
  const int BIGN = 1 << 30;

  // 0. convert x + weights to bf16
  cvt_k<<<(CVT_TOTAL / 8 + 255) / 256, blk, 0, stream>>>(
      x, (const float*)d_in[1], (const float*)d_in[10],
      (const float*)d_in[4], (const float*)d_in[13],
      (const float*)d_in[5], (const float*)d_in[14],
      (const float*)d_in[9], (const float*)d_in[18],
      (const float*)d_in[19], wb);

  // 1. in-proj: [xi|z][dir] = (flip?)xb @ in_w^T, split-written dense (64x64 tiles)
  gemm_bt<64,64><<<dim3(16, 64, 2), blk, 0, stream>>>(
      xb, inw, inw + 4194304L, (void*)xi, (void*)zb, 2048,
      1024, 4096, 1024, 1024, 1024, 2048,
      0L, (long)1024 * 2048, nullptr, nullptr, 1, 1, 0, nullptr, 0);

  // 2. depthwise conv + silu -> u
  conv_silu_k<<<2048, blk, 0, stream>>>(xi, fw_conv_w, bw_conv_w, fw_conv_b, bw_conv_b, u);

  // 3. x_dbl = u @ xproj_w^T   (N=96)
  gemm_bt<32,64><<<dim3(32, 2, 2), blk, 0, stream>>>(
      u, xprojw, xprojw + 196608L, (void*)xdbl, nullptr, BIGN,
      1024, 96, 2048, 2048, 2048, 96,
      (long)1024 * 2048, (long)1024 * 96, nullptr, nullptr, 0, 1, 0, nullptr, 0);

  // 4. delta = softplus(dt @ dt_w^T + dt_b) -> dense over dead xi (ldc=2048)
  gemm_bt<32,64><<<dim3(32, 32, 2), blk, 0, stream>>>(
      xdbl, dtw, dtw + 131072L, (void*)delta, nullptr, BIGN,
      1024, 2048, 64, 96, 64, 2048,
      (long)1024 * 96, (long)1024 * 2048, fw_dt_b, bw_dt_b, 0, 1, 1, nullptr, 0);

  // 5. chunk-parallel scan: p1 local -> p2 combine -> p3 rescan+gate
  scan_p1<<<dim3(8, NC, 2), blk, 0, stream>>>(delta, u, xdbl, fw_Alog, bw_Alog, hout, sumd);
  scan_p2<<<dim3(256), blk, 0, stream>>>(fw_Alog, bw_Alog, hout, sumd);
  scan_p3<<<dim3(8, NC, 2), blk, 0, stream>>>(delta, zb, u, xdbl, fw_Alog, bw_Alog,
                                              fw_Dp, bw_Dp, hout, g);

  // 6. out-proj + residual + unflip + concat -> fused (bf16 [1024][2048])
  gemm_bt<32,64><<<dim3(32, 16, 2), blk, 0, stream>>>(
      g, outw, outw + 2097152L, (void*)fused, nullptr, BIGN,
      1024, 1024, 2048, 2048, 2048, 1024,
      (long)1024 * 2048, 0L, nullptr, nullptr, 0, 1, 0, x, 1);

  // 7. final proj: fin = fused @ proj_w^T (fp32 out)
  gemm_bt<32,64><<<dim3(32, 16, 1), blk, 0, stream>>>(
      fused, projw, projw, (void*)fin, nullptr, BIGN,
      1024, 1024, 2048, 2048, 2048, 1024,
      0L, 0L, nullptr, nullptr, 0, 0, 0, nullptr, 0);

  // 8. +proj_b, LayerNorm -> d_out (fp32)
  ln_k<<<1024, blk, 0, stream>>>(fin, proj_b, ln_w, ln_b, (float*)d_out);
}